// Round 12
// baseline (274.980 us; speedup 1.0000x reference)
//
#include <hip/hip_runtime.h>

#define TT  200
#define IN  5
#define NH  32
#define FC1 20
#define CH  16        // steps per chunk (gx buffer depth)

// ws layout (dword units):
//  [0,2048):    whh f16 pairs, lane-packed: l*32 + r'*8 + j
//               lane l=(u,p): row (u&31)+32r', dims (16p+2j, 16p+2j+1)
//  [2048,3584): wih f16 pairs: row*12 + j  (pairs j=0..9 of 20 dims, 2 pad)
//  [3584,3712): bias f32[128] = b_ih + b_hh
#define WS_WHH  0
#define WS_WIH  2048
#define WS_BIAS 3584

typedef _Float16 h2t __attribute__((ext_vector_type(2)));

#if __has_builtin(__builtin_amdgcn_fdot2)
#define FDOT2(a, b, c) __builtin_amdgcn_fdot2((a), (b), (c), false)
#else
__device__ __forceinline__ float FDOT2(h2t a, h2t b, float c) {
    return fmaf((float)a.x, (float)b.x, fmaf((float)a.y, (float)b.y, c));
}
#endif

__device__ __forceinline__ float sigm(float a) {
    return __builtin_amdgcn_rcpf(1.f + __expf(-a));
}
__device__ __forceinline__ float tanh_f(float a) {
    return fmaf(2.f, __builtin_amdgcn_rcpf(1.f + __expf(-2.f * a)), -1.f);
}

__device__ __forceinline__ h2t bc_h2(unsigned int v) {
    return __builtin_bit_cast(h2t, v);
}

// ---- prep: pack whh (lane layout), wih (row pairs), bias into ws ----
__global__ __launch_bounds__(256) void prep_w(
    const float* __restrict__ w_ih, const float* __restrict__ w_hh,
    const float* __restrict__ b_ih, const float* __restrict__ b_hh,
    unsigned int* __restrict__ ws)
{
    const int tid = blockIdx.x * 256 + threadIdx.x;
    if (tid < 2048) {
        // whh: lane l, r' = (k>>3), j = k&7
        const int l = tid >> 5, k = tid & 31;
        const int rp = k >> 3, j = k & 7;
        const int row = (l & 31) + 32 * rp;
        const int d0  = 16 * (l >> 5) + 2 * j;
        h2t hv = { (_Float16)w_hh[row * NH + d0],
                   (_Float16)w_hh[row * NH + d0 + 1] };
        ws[WS_WHH + tid] = __builtin_bit_cast(unsigned int, hv);
    } else if (tid < 3584) {
        const int t = tid - 2048;
        const int row = t / 12, j = t % 12;
        const int d0 = 2 * j;
        float a = 0.f, b = 0.f;
        if (d0 < FC1) { a = w_ih[row * FC1 + d0]; b = w_ih[row * FC1 + d0 + 1]; }
        h2t hv = { (_Float16)a, (_Float16)b };
        ws[WS_WIH + (row * 12 + j)] = __builtin_bit_cast(unsigned int, hv);
    } else if (tid < 3712) {
        const int r = tid - 3584;
        ((float*)(ws + WS_BIAS))[r] = b_ih[r] + b_hh[r];
    }
}

// One wave per batch element. Lane l = (u = l&31, p = l>>5).
// K-split over h: lane owns gate rows {u,u+32,u+64,u+96} x h-dims [16p,16p+16).
// gx = bias + W_ih*h20 precomputed per 16-step chunk into LDS (f32).
// gx is seeded into the p=0 partial ONLY (the cross-half combine adds the
// halves, so gx must appear exactly once).
__global__ __launch_bounds__(64) void lstm_fused(
    const float* __restrict__ x,      // [B,200,5]
    const float* __restrict__ fc1_w,  // [20,5]
    const float* __restrict__ fc1_b,  // [20]
    const unsigned int* __restrict__ ws,
    const float* __restrict__ fc2_w,  // [2,32]
    const float* __restrict__ fc2_b,  // [2]
    float* __restrict__ out)          // [B,2]
{
    const int b = blockIdx.x;
    const int l = threadIdx.x;
    const int u = l & 31;
    const int p = l >> 5;

    __shared__ __align__(16) float4 gx[CH * 32];   // 8 KB: [k][slot u] = (i,f,g,o)
    __shared__ __align__(16) float4 dcomb[64];     // 1 KB
    __shared__ __align__(16) _Float16 sh_h[NH];    // 64 B

    // ---- W_hh for this lane: 8 dwordx4 (contiguous, one base) ----
    h2t whh[32];   // [r'][j]: row (u+32r'), dim-pair (16p+2j)
    {
        const uint4* wp = (const uint4*)(ws + WS_WHH + l * 32);
        #pragma unroll
        for (int g = 0; g < 8; ++g) {
            uint4 v = wp[g];
            whh[4*g+0] = bc_h2(v.x); whh[4*g+1] = bc_h2(v.y);
            whh[4*g+2] = bc_h2(v.z); whh[4*g+3] = bc_h2(v.w);
        }
    }

    if (l < 16) ((unsigned int*)sh_h)[l] = 0u;
    float c = 0.f;

    const int   tq = l & 15;       // prep: step within chunk
    const int   q  = l >> 4;       // prep: slot quarter (slots 8q..8q+7)
    const float* xb = x + (size_t)b * (TT * IN);
    const float* biasf = (const float*)(ws + WS_BIAS);

    for (int tc = 0; tc < TT; tc += CH) {
        // ================= prep: gx for steps tc..tc+15 =================
        {
            const int t = tc + tq;
            if (t < TT) {
                // fc1: h20 = relu(fc1_w * x[t] + fc1_b)   (uniform weights)
                float xv[IN];
                #pragma unroll
                for (int i = 0; i < IN; ++i) xv[i] = xb[t * IN + i];
                h2t h20p[10];
                #pragma unroll
                for (int j = 0; j < FC1; j += 2) {
                    float a0 = fc1_b[j], a1 = fc1_b[j + 1];
                    #pragma unroll
                    for (int i = 0; i < IN; ++i) {
                        a0 = fmaf(fc1_w[j * IN + i],       xv[i], a0);
                        a1 = fmaf(fc1_w[(j + 1) * IN + i], xv[i], a1);
                    }
                    h20p[j >> 1] = h2t{(_Float16)fmaxf(a0, 0.f),
                                       (_Float16)fmaxf(a1, 0.f)};
                }
                // gx rows for slots 8q..8q+7
                #pragma unroll
                for (int s = 0; s < 8; ++s) {
                    const int uslot = 8 * q + s;
                    float dacc[4];
                    #pragma unroll
                    for (int m = 0; m < 4; ++m) {
                        const int row = uslot + 32 * m;
                        const uint4* wr = (const uint4*)(ws + WS_WIH + row * 12);
                        uint4 w0 = wr[0], w1 = wr[1];
                        uint4 w2 = wr[2];
                        float a0 = biasf[row], a1 = 0.f;
                        a0 = FDOT2(bc_h2(w0.x), h20p[0], a0);
                        a1 = FDOT2(bc_h2(w0.y), h20p[1], a1);
                        a0 = FDOT2(bc_h2(w0.z), h20p[2], a0);
                        a1 = FDOT2(bc_h2(w0.w), h20p[3], a1);
                        a0 = FDOT2(bc_h2(w1.x), h20p[4], a0);
                        a1 = FDOT2(bc_h2(w1.y), h20p[5], a1);
                        a0 = FDOT2(bc_h2(w1.z), h20p[6], a0);
                        a1 = FDOT2(bc_h2(w1.w), h20p[7], a1);
                        a0 = FDOT2(bc_h2(w2.x), h20p[8], a0);
                        a1 = FDOT2(bc_h2(w2.y), h20p[9], a1);
                        dacc[m] = a0 + a1;
                    }
                    gx[tq * 32 + uslot] =
                        make_float4(dacc[0], dacc[1], dacc[2], dacc[3]);
                }
            }
        }
        __syncthreads();

        // ================= recurrence: 16 steps =================
        const int te = (TT - tc < CH) ? (TT - tc) : CH;
        for (int k = 0; k < te; ++k) {
            // gx slot (broadcast b128); seed into p=0 half ONLY
            const float4 g4 = gx[k * 32 + u];
            const float sd0 = (p == 0) ? g4.x : 0.f;
            const float sd1 = (p == 0) ? g4.y : 0.f;
            const float sd2 = (p == 0) ? g4.z : 0.f;
            const float sd3 = (p == 0) ? g4.w : 0.f;
            // this half's h dims: 32 bytes = 2 b128 reads
            h2t xin[8];
            {
                const uint4* hp = (const uint4*)((const char*)sh_h + 32 * p);
                uint4 h0 = hp[0], h1 = hp[1];
                xin[0] = bc_h2(h0.x); xin[1] = bc_h2(h0.y);
                xin[2] = bc_h2(h0.z); xin[3] = bc_h2(h0.w);
                xin[4] = bc_h2(h1.x); xin[5] = bc_h2(h1.y);
                xin[6] = bc_h2(h1.z); xin[7] = bc_h2(h1.w);
            }
            // 4 rows x 8 pairs, 2 chains each
            float dA[4];
            #pragma unroll
            for (int m = 0; m < 4; ++m) {
                float a0 = (m == 0) ? sd0 : (m == 1) ? sd1 : (m == 2) ? sd2 : sd3;
                float a1 = 0.f;
                a0 = FDOT2(whh[8*m+0], xin[0], a0);
                a1 = FDOT2(whh[8*m+1], xin[1], a1);
                a0 = FDOT2(whh[8*m+2], xin[2], a0);
                a1 = FDOT2(whh[8*m+3], xin[3], a1);
                a0 = FDOT2(whh[8*m+4], xin[4], a0);
                a1 = FDOT2(whh[8*m+5], xin[5], a1);
                a0 = FDOT2(whh[8*m+6], xin[6], a0);
                a1 = FDOT2(whh[8*m+7], xin[7], a1);
                dA[m] = a0 + a1;
            }
            // combine the two K-halves via LDS (same-wave FIFO)
            dcomb[l] = make_float4(dA[0], dA[1], dA[2], dA[3]);
            asm volatile("" ::: "memory");
            const float4 dp = dcomb[l ^ 32];
            const float gi = sigm(dA[0] + dp.x);
            const float gf = sigm(dA[1] + dp.y);
            const float gg = tanh_f(dA[2] + dp.z);
            const float go = sigm(dA[3] + dp.w);
            c = fmaf(gf, c, gi * gg);
            const float hval = go * tanh_f(c);
            if (p == 0) sh_h[u] = (_Float16)hval;
            asm volatile("" ::: "memory");
        }
        __syncthreads();   // gx consumed before next chunk overwrites
    }

    // ---- fc2 on final h ----
    if (l < 2) {
        float acc = fc2_b[l];
        #pragma unroll
        for (int k = 0; k < NH; ++k)
            acc = fmaf(fc2_w[l * NH + k], (float)sh_h[k], acc);
        out[(size_t)b * 2 + l] = acc;
    }
}

extern "C" void kernel_launch(void* const* d_in, const int* in_sizes, int n_in,
                              void* d_out, int out_size, void* d_ws, size_t ws_size,
                              hipStream_t stream) {
    const float* x     = (const float*)d_in[0];
    const float* fc1_w = (const float*)d_in[1];
    const float* fc1_b = (const float*)d_in[2];
    const float* w_ih  = (const float*)d_in[3];
    const float* w_hh  = (const float*)d_in[4];
    const float* b_ih  = (const float*)d_in[5];
    const float* b_hh  = (const float*)d_in[6];
    const float* fc2_w = (const float*)d_in[7];
    const float* fc2_b = (const float*)d_in[8];
    float* out = (float*)d_out;
    unsigned int* ws = (unsigned int*)d_ws;

    const int B = in_sizes[0] / (TT * IN);
    prep_w<<<dim3(15), dim3(256), 0, stream>>>(w_ih, w_hh, b_ih, b_hh, ws);
    lstm_fused<<<dim3(B), dim3(64), 0, stream>>>(
        x, fc1_w, fc1_b, ws, fc2_w, fc2_b, out);
}

// Round 13
// 218.336 us; speedup vs baseline: 1.2594x; 1.2594x over previous
//
#include <hip/hip_runtime.h>

#define TT  200
#define IN  5
#define NH  32
#define FC1 20
#define CH  64
#define RSG 12          // h20 row stride in dwords (48 B)

// ws layout (dword units):
//  [0,2048):      whh f16 pairs, lane-packed: l*32 + m*8 + j
//                 lane l=(u,p): row (l&31)+32m, dims (16p+2j, 16p+2j+1)
//  [2048,7168):   wih f16 pairs, lane-packed: l*20 + m*5 + jj
//                 lane l=(u,p): row (l&31)+32m, dims (10p+2jj, 10p+2jj+1)
//  [7168,7296):   bias f32[128] = b_ih + b_hh
//  [8192, ...):   h20 table (GH path): row r=b*TT+t, 12 dwords (10 h2 pairs)
#define WS_WHH  0
#define WS_WIH  2048
#define WS_BIAS 7168
#define WS_H20  8192

typedef _Float16 h2t __attribute__((ext_vector_type(2)));

#if __has_builtin(__builtin_amdgcn_fdot2)
#define FDOT2(a, b, c) __builtin_amdgcn_fdot2((a), (b), (c), false)
#else
__device__ __forceinline__ float FDOT2(h2t a, h2t b, float c) {
    return fmaf((float)a.x, (float)b.x, fmaf((float)a.y, (float)b.y, c));
}
#endif

__device__ __forceinline__ float sigm(float a) {
    return __builtin_amdgcn_rcpf(1.f + __expf(-a));
}
__device__ __forceinline__ float tanh_f(float a) {
    return fmaf(2.f, __builtin_amdgcn_rcpf(1.f + __expf(-2.f * a)), -1.f);
}
__device__ __forceinline__ h2t bc_h2(unsigned int v) {
    return __builtin_bit_cast(h2t, v);
}
__device__ __forceinline__ unsigned int h2bits(float a, float b) {
    return __builtin_bit_cast(unsigned int, h2t{(_Float16)a, (_Float16)b});
}

// ---- prep: pack whh/wih (lane layouts) + bias into ws ----
__global__ __launch_bounds__(256) void prep_w(
    const float* __restrict__ w_ih, const float* __restrict__ w_hh,
    const float* __restrict__ b_ih, const float* __restrict__ b_hh,
    unsigned int* __restrict__ ws)
{
    const int tid = blockIdx.x * 256 + threadIdx.x;
    if (tid < 2048) {
        const int l = tid >> 5, k = tid & 31;
        const int m = k >> 3, j = k & 7;
        const int row = (l & 31) + 32 * m;
        const int d0  = 16 * (l >> 5) + 2 * j;
        ws[WS_WHH + tid] = h2bits(w_hh[row * NH + d0], w_hh[row * NH + d0 + 1]);
    } else if (tid < 7168) {
        const int t2 = tid - WS_WIH;
        const int l = t2 / 20, k = t2 % 20;
        const int m = k / 5, jj = k % 5;
        const int row = (l & 31) + 32 * m;
        const int d0  = 10 * (l >> 5) + 2 * jj;
        ws[WS_WIH + t2] = h2bits(w_ih[row * FC1 + d0], w_ih[row * FC1 + d0 + 1]);
    } else if (tid < 7296) {
        const int r = tid - WS_BIAS;
        ((float*)(ws + WS_BIAS))[r] = b_ih[r] + b_hh[r];
    }
}

// ---- prep (GH path): h20[b,t] = relu(fc1(x[b,t])) for all rows ----
__global__ __launch_bounds__(256) void prep_h20(
    const float* __restrict__ x, const float* __restrict__ fc1_w,
    const float* __restrict__ fc1_b, unsigned int* __restrict__ ws, int nrows)
{
    const int r = blockIdx.x * 256 + threadIdx.x;
    if (r >= nrows) return;
    const float* xr = x + (size_t)r * IN;
    float xv[IN];
    #pragma unroll
    for (int i = 0; i < IN; ++i) xv[i] = xr[i];
    unsigned int ow[10];
    #pragma unroll
    for (int j = 0; j < FC1; j += 2) {
        float a0 = fc1_b[j], a1 = fc1_b[j + 1];
        #pragma unroll
        for (int i = 0; i < IN; ++i) {
            a0 = fmaf(fc1_w[j * IN + i],       xv[i], a0);
            a1 = fmaf(fc1_w[(j + 1) * IN + i], xv[i], a1);
        }
        ow[j >> 1] = h2bits(fmaxf(a0, 0.f), fmaxf(a1, 0.f));
    }
    unsigned int* dst = ws + WS_H20 + (size_t)r * RSG;
    *(uint4*)(dst)     = uint4{ow[0], ow[1], ow[2], ow[3]};
    *(uint4*)(dst + 4) = uint4{ow[4], ow[5], ow[6], ow[7]};
    *(uint2*)(dst + 8) = uint2{ow[8], ow[9]};
}

// One step: Q0/Q1/Q2 hold the h20 row (pairs 0-3 / 4-7 / 8-9).
#define STEP(Q0, Q1, Q2)                                                      \
  {                                                                           \
    const uint4* hp_ = (const uint4*)((const char*)sh_h + 32 * p);            \
    uint4 h0_ = hp_[0], h1_ = hp_[1];                                         \
    h2t e0_ = bc_h2(p ? (Q1).y : (Q0).x);                                     \
    h2t e1_ = bc_h2(p ? (Q1).z : (Q0).y);                                     \
    h2t e2_ = bc_h2(p ? (Q1).w : (Q0).z);                                     \
    h2t e3_ = bc_h2(p ? (Q2).x : (Q0).w);                                     \
    h2t e4_ = bc_h2(p ? (Q2).y : (Q1).x);                                     \
    float dA_[4];                                                             \
    _Pragma("unroll")                                                         \
    for (int m = 0; m < 4; ++m) {                                             \
      float a0_ = sd[m], a1_ = 0.f;                                           \
      a0_ = FDOT2(wihr[5*m+0], e0_, a0_);                                     \
      a1_ = FDOT2(wihr[5*m+1], e1_, a1_);                                     \
      a0_ = FDOT2(wihr[5*m+2], e2_, a0_);                                     \
      a1_ = FDOT2(wihr[5*m+3], e3_, a1_);                                     \
      a0_ = FDOT2(wihr[5*m+4], e4_, a0_);                                     \
      a1_ = FDOT2(whh[8*m+0], bc_h2(h0_.x), a1_);                             \
      a0_ = FDOT2(whh[8*m+1], bc_h2(h0_.y), a0_);                             \
      a1_ = FDOT2(whh[8*m+2], bc_h2(h0_.z), a1_);                             \
      a0_ = FDOT2(whh[8*m+3], bc_h2(h0_.w), a0_);                             \
      a1_ = FDOT2(whh[8*m+4], bc_h2(h1_.x), a1_);                             \
      a0_ = FDOT2(whh[8*m+5], bc_h2(h1_.y), a0_);                             \
      a1_ = FDOT2(whh[8*m+6], bc_h2(h1_.z), a1_);                             \
      a0_ = FDOT2(whh[8*m+7], bc_h2(h1_.w), a0_);                             \
      dA_[m] = a0_ + a1_;                                                     \
    }                                                                         \
    dcomb[l] = make_float4(dA_[0], dA_[1], dA_[2], dA_[3]);                   \
    asm volatile("" ::: "memory");                                            \
    const float4 dp_ = dcomb[l ^ 32];                                         \
    const float gi_ = sigm(dA_[0] + dp_.x);                                   \
    const float gf_ = sigm(dA_[1] + dp_.y);                                   \
    const float gg_ = tanh_f(dA_[2] + dp_.z);                                 \
    const float go_ = sigm(dA_[3] + dp_.w);                                   \
    c = fmaf(gf_, c, gi_ * gg_);                                              \
    const float hv_ = go_ * tanh_f(c);                                        \
    if (p == 0) sh_h[u] = (_Float16)hv_;                                      \
    asm volatile("" ::: "memory");                                            \
  }

// One wave per batch element. Lane l = (u = l&31, p = l>>5).
// K-split over BOTH W_ih and W_hh: lane owns gate rows {u+32m} x its half of
// [h20(20) | h(32)]; halves combine via dcomb LDS (same-wave FIFO). gx never
// materialized. GH=true: h20 rows stream from ws via uniform VMEM loads.
template <bool GH>
__global__ __attribute__((amdgpu_waves_per_eu(4, 4))) __launch_bounds__(64)
void lstm_fused(
    const float* __restrict__ x,
    const float* __restrict__ fc1_w,
    const float* __restrict__ fc1_b,
    const unsigned int* __restrict__ ws,
    const float* __restrict__ fc2_w,
    const float* __restrict__ fc2_b,
    float* __restrict__ out)
{
    const int b = blockIdx.x;
    const int l = threadIdx.x;
    const int u = l & 31;
    const int p = l >> 5;

    __shared__ __align__(16) float4 dcomb[64];     // 1 KB
    __shared__ __align__(16) _Float16 sh_h[NH];    // 64 B

    // weights (pre-converted f16 pairs; cheap even if the scheduler re-loads)
    h2t whh[32];
    {
        const uint4* wp = (const uint4*)(ws + WS_WHH + l * 32);
        #pragma unroll
        for (int g = 0; g < 8; ++g) {
            uint4 v = wp[g];
            whh[4*g+0] = bc_h2(v.x); whh[4*g+1] = bc_h2(v.y);
            whh[4*g+2] = bc_h2(v.z); whh[4*g+3] = bc_h2(v.w);
        }
    }
    h2t wihr[20];
    {
        const uint4* wp = (const uint4*)(ws + WS_WIH + l * 20);
        #pragma unroll
        for (int g = 0; g < 5; ++g) {
            uint4 v = wp[g];
            wihr[4*g+0] = bc_h2(v.x); wihr[4*g+1] = bc_h2(v.y);
            wihr[4*g+2] = bc_h2(v.z); wihr[4*g+3] = bc_h2(v.w);
        }
    }
    const float* biasf = (const float*)(ws + WS_BIAS);
    float sd[4];
    #pragma unroll
    for (int m = 0; m < 4; ++m) sd[m] = (p == 0) ? biasf[u + 32 * m] : 0.f;

    if (l < 16) ((unsigned int*)sh_h)[l] = 0u;
    asm volatile("" ::: "memory");
    float c = 0.f;

    if constexpr (GH) {
        const unsigned int* h20p = ws + WS_H20 + (size_t)b * TT * RSG;
        uint4 qa0, qa1; uint2 qa2;
        uint4 qb0, qb1; uint2 qb2;
#define LOADROW(Q0, Q1, Q2, t)                                                \
        { const unsigned int* rp_ = h20p + (size_t)(t) * RSG;                 \
          (Q0) = *(const uint4*)(rp_);                                        \
          (Q1) = *(const uint4*)(rp_ + 4);                                    \
          (Q2) = *(const uint2*)(rp_ + 8); }
        LOADROW(qa0, qa1, qa2, 0);
        for (int t = 0; t < TT; t += 2) {
            LOADROW(qb0, qb1, qb2, t + 1);            // prefetch before fences
            STEP(qa0, qa1, qa2);
            const int t2 = (t + 2 < TT) ? (t + 2) : (TT - 1);
            LOADROW(qa0, qa1, qa2, t2);
            STEP(qb0, qb1, qb2);
        }
#undef LOADROW
    } else {
        __shared__ __align__(16) unsigned int h20c[CH * RSG];   // 3 KB
        const float* xb = x + (size_t)b * (TT * IN);
        for (int tc = 0; tc < TT; tc += CH) {
            {   // refill: lane l computes h20 row for t = tc + l
                const int t = tc + l;
                if (t < TT) {
                    float xv[IN];
                    #pragma unroll
                    for (int i = 0; i < IN; ++i) xv[i] = xb[t * IN + i];
                    unsigned int ow[10];
                    #pragma unroll
                    for (int j = 0; j < FC1; j += 2) {
                        float a0 = fc1_b[j], a1 = fc1_b[j + 1];
                        #pragma unroll
                        for (int i = 0; i < IN; ++i) {
                            a0 = fmaf(fc1_w[j * IN + i],       xv[i], a0);
                            a1 = fmaf(fc1_w[(j + 1) * IN + i], xv[i], a1);
                        }
                        ow[j >> 1] = h2bits(fmaxf(a0, 0.f), fmaxf(a1, 0.f));
                    }
                    unsigned int* dst = h20c + l * RSG;
                    *(uint4*)(dst)     = uint4{ow[0], ow[1], ow[2], ow[3]};
                    *(uint4*)(dst + 4) = uint4{ow[4], ow[5], ow[6], ow[7]};
                    *(uint2*)(dst + 8) = uint2{ow[8], ow[9]};
                }
            }
            __syncthreads();
            const int te = (TT - tc < CH) ? (TT - tc) : CH;
            for (int k = 0; k < te; ++k) {
                const unsigned int* rp_ = h20c + k * RSG;
                uint4 q0 = *(const uint4*)(rp_);
                uint4 q1 = *(const uint4*)(rp_ + 4);
                uint2 q2 = *(const uint2*)(rp_ + 8);
                STEP(q0, q1, q2);
            }
            __syncthreads();
        }
    }

    // fc2 on final h
    if (l < 2) {
        float acc = fc2_b[l];
        #pragma unroll
        for (int k = 0; k < NH; ++k)
            acc = fmaf(fc2_w[l * NH + k], (float)sh_h[k], acc);
        out[(size_t)b * 2 + l] = acc;
    }
}

extern "C" void kernel_launch(void* const* d_in, const int* in_sizes, int n_in,
                              void* d_out, int out_size, void* d_ws, size_t ws_size,
                              hipStream_t stream) {
    const float* x     = (const float*)d_in[0];
    const float* fc1_w = (const float*)d_in[1];
    const float* fc1_b = (const float*)d_in[2];
    const float* w_ih  = (const float*)d_in[3];
    const float* w_hh  = (const float*)d_in[4];
    const float* b_ih  = (const float*)d_in[5];
    const float* b_hh  = (const float*)d_in[6];
    const float* fc2_w = (const float*)d_in[7];
    const float* fc2_b = (const float*)d_in[8];
    float* out = (float*)d_out;
    unsigned int* ws = (unsigned int*)d_ws;

    const int B = in_sizes[0] / (TT * IN);
    const int nrows = B * TT;
    const size_t need = ((size_t)WS_H20 + (size_t)nrows * RSG) * 4;

    prep_w<<<dim3(29), dim3(256), 0, stream>>>(w_ih, w_hh, b_ih, b_hh, ws);
    if (ws_size >= need) {
        prep_h20<<<dim3((nrows + 255) / 256), dim3(256), 0, stream>>>(
            x, fc1_w, fc1_b, ws, nrows);
        lstm_fused<true><<<dim3(B), dim3(64), 0, stream>>>(
            x, fc1_w, fc1_b, ws, fc2_w, fc2_b, out);
    } else {
        lstm_fused<false><<<dim3(B), dim3(64), 0, stream>>>(
            x, fc1_w, fc1_b, ws, fc2_w, fc2_b, out);
    }
}